// Round 7
// baseline (396.034 us; speedup 1.0000x reference)
//
#include <hip/hip_runtime.h>

typedef unsigned short u16;
typedef unsigned short u16x4 __attribute__((ext_vector_type(4), may_alias));
typedef unsigned short u16x8 __attribute__((ext_vector_type(8), may_alias));
typedef __bf16 bf16x8 __attribute__((ext_vector_type(8), may_alias));
typedef float f32x4 __attribute__((ext_vector_type(4), may_alias));

typedef __attribute__((address_space(1))) void gvoid_t;
typedef __attribute__((address_space(3))) void lvoid_t;

__device__ __forceinline__ void gld16(const void* g, void* l) {
    __builtin_amdgcn_global_load_lds((gvoid_t*)g, (lvoid_t*)l, 16, 0, 0);
}

__device__ __forceinline__ u16 f2bf(float f) {
    unsigned u = __builtin_bit_cast(unsigned, f);
    u += 0x7fffu + ((u >> 16) & 1u);
    return (u16)(u >> 16);
}

__device__ __forceinline__ unsigned cvt_pk_bf16(float lo, float hi) {
    unsigned r;
    asm("v_cvt_pk_bf16_f32 %0, %1, %2" : "=v"(r) : "v"(lo), "v"(hi));
    return r;
}

#define KSCALE 0.18033688011112042f  /* 0.125 * log2(e) */

// ---------------- fp32 -> bf16 elementwise ----------------
__global__ __launch_bounds__(256) void cvt_f32_bf16_k(const float* __restrict__ in,
                                                      u16* __restrict__ out, int n8) {
    int i = blockIdx.x * 256 + threadIdx.x;
    if (i >= n8) return;
    float4 a = reinterpret_cast<const float4*>(in)[2 * i];
    float4 c = reinterpret_cast<const float4*>(in)[2 * i + 1];
    u16x8 o;
    o[0] = f2bf(a.x); o[1] = f2bf(a.y); o[2] = f2bf(a.z); o[3] = f2bf(a.w);
    o[4] = f2bf(c.x); o[5] = f2bf(c.y); o[6] = f2bf(c.z); o[7] = f2bf(c.w);
    reinterpret_cast<u16x8*>(out)[i] = o;
}

// ---------------- fp32 [R][C] -> bf16 [C][R] transpose ----------------
__global__ __launch_bounds__(256) void tr_f32_bf16_k(const float* __restrict__ in,
                                                     u16* __restrict__ out, int R, int C) {
    __shared__ u16 t[64][73];
    int tc = C >> 6;
    int r0 = (blockIdx.x / tc) << 6, c0 = (blockIdx.x % tc) << 6;
    int lr = threadIdx.x >> 2;
    int lc = (threadIdx.x & 3) << 4;
    const float* src = in + (size_t)(r0 + lr) * C + c0 + lc;
#pragma unroll
    for (int j = 0; j < 16; j += 4) {
        float4 v = *reinterpret_cast<const float4*>(src + j);
        t[lr][lc + j + 0] = f2bf(v.x);
        t[lr][lc + j + 1] = f2bf(v.y);
        t[lr][lc + j + 2] = f2bf(v.z);
        t[lr][lc + j + 3] = f2bf(v.w);
    }
    __syncthreads();
    u16x8 o0, o1;
#pragma unroll
    for (int j = 0; j < 8; j++) { o0[j] = t[lc + j][lr]; o1[j] = t[lc + 8 + j][lr]; }
    u16* dst = out + (size_t)(c0 + lr) * R + r0 + lc;
    *reinterpret_cast<u16x8*>(dst) = o0;
    *reinterpret_cast<u16x8*>(dst + 8) = o1;
}

// ---------------- bf16 GEMM: C = A[M][K] * Bt[N][K]^T + bias ----------------
template <int MODE>
__global__ __launch_bounds__(256) void gemm_bt_k(const u16* __restrict__ A,
                                                 const u16* __restrict__ Bt,
                                                 const float* __restrict__ bias,
                                                 u16* __restrict__ Qp, u16* __restrict__ Kp,
                                                 u16* __restrict__ Vt,
                                                 float* __restrict__ Cf,
                                                 int M, int N, int K) {
    __shared__ u16 As[2][128 * 64];
    __shared__ u16 Bs[2][128 * 64];
    const int tid = threadIdx.x;
    const int l = tid & 63, w = tid >> 6;
    const int wm = w >> 1, wn = w & 1;
    const int l16 = l & 15, lg = l >> 4;
    const int tc = N >> 7;
    const int bm = blockIdx.x / tc, bn = blockIdx.x % tc;
    const u16* Ab = A + (size_t)(bm << 7) * K;
    const u16* Bb = Bt + (size_t)(bn << 7) * K;

    f32x4 acc[4][4];
#pragma unroll
    for (int mi = 0; mi < 4; mi++)
#pragma unroll
        for (int ni = 0; ni < 4; ni++)
#pragma unroll
            for (int q = 0; q < 4; q++) acc[mi][ni][q] = 0.f;

    auto stage = [&](int buf, int k0) {
#pragma unroll
        for (int i = 0; i < 4; i++) {
            int s = tid + (i << 8);
            int ub = ((i << 8) + (w << 6)) << 3;
            gld16(Ab + (size_t)(s >> 3) * K + k0 + ((s & 7) << 3), &As[buf][ub]);
            gld16(Bb + (size_t)(s >> 3) * K + k0 + ((s & 7) << 3), &Bs[buf][ub]);
        }
    };

    stage(0, 0);
    int cur = 0;
    for (int k0 = 0; k0 < K; k0 += 64) {
        __syncthreads();
        if (k0 + 64 < K) stage(cur ^ 1, k0 + 64);
        const u16* Asc = As[cur];
        const u16* Bsc = Bs[cur];
#pragma unroll
        for (int kk = 0; kk < 2; kk++) {
            bf16x8 af[4], bfr[4];
#pragma unroll
            for (int mi = 0; mi < 4; mi++)
                af[mi] = *reinterpret_cast<const bf16x8*>(
                    &Asc[((wm << 6) + (mi << 4) + l16) * 64 + (kk << 5) + (lg << 3)]);
#pragma unroll
            for (int ni = 0; ni < 4; ni++)
                bfr[ni] = *reinterpret_cast<const bf16x8*>(
                    &Bsc[((wn << 6) + (ni << 4) + l16) * 64 + (kk << 5) + (lg << 3)]);
#pragma unroll
            for (int mi = 0; mi < 4; mi++)
#pragma unroll
                for (int ni = 0; ni < 4; ni++)
                    acc[mi][ni] = __builtin_amdgcn_mfma_f32_16x16x32_bf16(af[mi], bfr[ni], acc[mi][ni], 0, 0, 0);
        }
        cur ^= 1;
    }

    const int rb = (bm << 7) + (wm << 6), cb = (bn << 7) + (wn << 6);
    if constexpr (MODE == 0) {
        const int sec = cb >> 10;
#pragma unroll
        for (int ni = 0; ni < 4; ni++) {
            const int col = cb + (ni << 4) + l16;
            const float bb = bias[col];
            const int d = col & 1023, h = d >> 6, dh = d & 63;
#pragma unroll
            for (int mi = 0; mi < 4; mi++) {
                const int row0 = rb + (mi << 4) + (lg << 2);
                const int bidx = row0 >> 11, n0 = row0 & 2047;
                const size_t base = (size_t)(bidx * 16 + h) * 131072;
                if (sec == 0) {
#pragma unroll
                    for (int r = 0; r < 4; r++)
                        Qp[base + (size_t)(n0 + r) * 64 + dh] = f2bf(acc[mi][ni][r] + bb);
                } else if (sec == 1) {
#pragma unroll
                    for (int r = 0; r < 4; r++)
                        Kp[base + (size_t)(n0 + r) * 64 + dh] = f2bf((acc[mi][ni][r] + bb) * KSCALE);
                } else {
                    u16x4 pk;
#pragma unroll
                    for (int r = 0; r < 4; r++) pk[r] = f2bf(acc[mi][ni][r] + bb);
                    *reinterpret_cast<u16x4*>(&Vt[base + (size_t)dh * 2048 + n0]) = pk;
                }
            }
        }
    } else {
#pragma unroll
        for (int ni = 0; ni < 4; ni++) {
            const int col = cb + (ni << 4) + l16;
            const float bb = bias[col];
#pragma unroll
            for (int mi = 0; mi < 4; mi++)
#pragma unroll
                for (int r = 0; r < 4; r++) {
                    const int row = rb + (mi << 4) + (lg << 2) + r;
                    Cf[(size_t)row * N + col] = acc[mi][ni][r] + bb;
                }
        }
    }
}

// ---------------- flash attention: 16-row q-tiles, 4096 uniform 33-iter waves ----------------
// qq in 0..127 (16 q-rows each); nt16(qq)=(qq>>2)+1. Wave = pair (qq=p, qq=127-p):
// total kv-iters = 33 exactly for every p in 0..63. Block = (bh, 4 p's); bh=blockIdx>>4
// so consecutive blocks share a head's K/V in L2.
__global__ __launch_bounds__(256, 4) void attn_k(const u16* __restrict__ Qp,
                                                 const u16* __restrict__ Kp,
                                                 const u16* __restrict__ Vt,
                                                 u16* __restrict__ Y) {
    __shared__ u16 P_lds[4][16 * 72];
    const int tid = threadIdx.x;
    const int l = tid & 63, w = tid >> 6;
    const int l16 = l & 15, lg = l >> 4;
    const int bh = blockIdx.x >> 4;
    const int p = (blockIdx.x & 15) * 4 + w;    // 0..63
    const int b = bh >> 4, h = bh & 15;
    const u16* Qb = Qp + (size_t)bh * 131072;
    const u16* Kb = Kp + (size_t)bh * 131072;
    const u16* Vb = Vt + (size_t)bh * 131072;
    u16* pl = &P_lds[w][0];

#pragma unroll 1
    for (int half = 0; half < 2; half++) {
        const int qq = half ? (127 - p) : p;
        const int nt = (qq >> 2) + 1;

        bf16x8 qf[2];
#pragma unroll
        for (int kk = 0; kk < 2; kk++)
            qf[kk] = *reinterpret_cast<const bf16x8*>(
                Qb + (size_t)(qq * 16 + l16) * 64 + kk * 32 + lg * 8);

        f32x4 o[4];
        float m_s = -1e30f, l_s = 0.f;
#pragma unroll
        for (int n = 0; n < 4; n++)
#pragma unroll
            for (int r = 0; r < 4; r++) o[n][r] = 0.f;

        // preload K tile 0
        bf16x8 kf[4][2];
#pragma unroll
        for (int t = 0; t < 4; t++)
#pragma unroll
            for (int kk = 0; kk < 2; kk++)
                kf[t][kk] = *reinterpret_cast<const bf16x8*>(
                    Kb + (size_t)(t * 16 + l16) * 64 + kk * 32 + lg * 8);

#pragma unroll 1
        for (int it = 0; it < nt; it++) {
            const int kv0 = it << 6;
            const bool diag = (it == nt - 1);
            // QK^T (swapped operands -> S^T; lane owns q-row l16, 16 kv in-lane)
            float s4[4][4];
#pragma unroll
            for (int t = 0; t < 4; t++) {
                f32x4 s;
                s[0] = s[1] = s[2] = s[3] = 0.f;
                s = __builtin_amdgcn_mfma_f32_16x16x32_bf16(kf[t][0], qf[0], s, 0, 0, 0);
                s = __builtin_amdgcn_mfma_f32_16x16x32_bf16(kf[t][1], qf[1], s, 0, 0, 0);
#pragma unroll
                for (int r = 0; r < 4; r++) s4[t][r] = s[r];
            }
            // reload K in place for NEXT iter (hidden under softmax+PV)
            {
                const int kvn = (it + 1 < nt) ? (kv0 + 64) : kv0;
#pragma unroll
                for (int t = 0; t < 4; t++)
#pragma unroll
                    for (int kk = 0; kk < 2; kk++)
                        kf[t][kk] = *reinterpret_cast<const bf16x8*>(
                            Kb + (size_t)(kvn + t * 16 + l16) * 64 + kk * 32 + lg * 8);
            }
            // V loads for THIS iter (consumed at iter end)
            bf16x8 v0[4], v1[4];
#pragma unroll
            for (int n = 0; n < 4; n++) {
                const u16* vr = Vb + (size_t)(n * 16 + l16) * 2048 + kv0 + lg * 8;
                v0[n] = *reinterpret_cast<const bf16x8*>(vr);
                v1[n] = *reinterpret_cast<const bf16x8*>(vr + 32);
            }
            if (diag) {
                const int qg = qq * 16 + l16;
                const int kvb = kv0 + lg * 4;
#pragma unroll
                for (int t = 0; t < 4; t++)
#pragma unroll
                    for (int r = 0; r < 4; r++)
                        if (kvb + t * 16 + r > qg) s4[t][r] = -1e30f;
            }
            float mt[4];
#pragma unroll
            for (int t = 0; t < 4; t++)
                mt[t] = fmaxf(fmaxf(s4[t][0], s4[t][1]), fmaxf(s4[t][2], s4[t][3]));
            float mx = fmaxf(fmaxf(mt[0], mt[1]), fmaxf(mt[2], mt[3]));
            mx = fmaxf(mx, __shfl_xor(mx, 16, 64));
            mx = fmaxf(mx, __shfl_xor(mx, 32, 64));
            if (__any(mx - m_s > 8.0f)) {
                float mn = fmaxf(m_s, mx);
                float al = __builtin_amdgcn_exp2f(m_s - mn);
                m_s = mn;
                l_s *= al;
#pragma unroll
                for (int r = 0; r < 4; r++) {
                    float ar = __shfl(al, lg * 4 + r, 64);
#pragma unroll
                    for (int n = 0; n < 4; n++) o[n][r] *= ar;
                }
            }
#pragma unroll
            for (int t = 0; t < 4; t++)
#pragma unroll
                for (int r = 0; r < 4; r++)
                    s4[t][r] = __builtin_amdgcn_exp2f(s4[t][r] - m_s);
            float st[4];
#pragma unroll
            for (int t = 0; t < 4; t++)
                st[t] = (s4[t][0] + s4[t][1]) + (s4[t][2] + s4[t][3]);
            float sm = (st[0] + st[1]) + (st[2] + st[3]);
            sm += __shfl_xor(sm, 16, 64);
            sm += __shfl_xor(sm, 32, 64);
            l_s += sm;
            // pack P via v_cvt_pk_bf16_f32: one 8B store per t
#pragma unroll
            for (int t = 0; t < 4; t++) {
                uint2 pk;
                pk.x = cvt_pk_bf16(s4[t][0], s4[t][1]);
                pk.y = cvt_pk_bf16(s4[t][2], s4[t][3]);
                *reinterpret_cast<uint2*>(pl + l16 * 72 + t * 16 + lg * 4) = pk;
            }
            bf16x8 pa[2];
#pragma unroll
            for (int kk2 = 0; kk2 < 2; kk2++)
                pa[kk2] = *reinterpret_cast<const bf16x8*>(pl + l16 * 72 + kk2 * 32 + lg * 8);
#pragma unroll
            for (int n = 0; n < 4; n++) {
                o[n] = __builtin_amdgcn_mfma_f32_16x16x32_bf16(pa[0], v0[n], o[n], 0, 0, 0);
                o[n] = __builtin_amdgcn_mfma_f32_16x16x32_bf16(pa[1], v1[n], o[n], 0, 0, 0);
            }
        }
        // epilogue for this qq
#pragma unroll
        for (int r = 0; r < 4; r++) {
            const float li = __shfl(l_s, lg * 4 + r, 64);
            const float inv = 1.0f / li;
            const size_t row = (size_t)(b * 2048 + qq * 16 + lg * 4 + r);
#pragma unroll
            for (int n = 0; n < 4; n++)
                Y[row * 1024 + h * 64 + n * 16 + l16] = f2bf(o[n][r] * inv);
        }
    }
}

extern "C" void kernel_launch(void* const* d_in, const int* in_sizes, int n_in,
                              void* d_out, int out_size, void* d_ws, size_t ws_size,
                              hipStream_t stream) {
    const float* x     = (const float*)d_in[0];
    const float* w_qkv = (const float*)d_in[1];
    const float* b_qkv = (const float*)d_in[2];
    const float* w_o   = (const float*)d_in[3];
    const float* b_o   = (const float*)d_in[4];
    float* out = (float*)d_out;

    u16* ws  = (u16*)d_ws;
    u16* xb  = ws;                 // [8192][1024] x bf16; reused as attention output Y
    u16* wqT = ws + 8388608;       // [3072][1024]
    u16* woT = ws + 11534336;      // [1024][1024]
    u16* Qp  = ws + 12582912;      // [64 bh][2048][64]
    u16* Kp  = ws + 20971520;      // [64 bh][2048][64] (pre-scaled by 0.125*log2e)
    u16* Vt  = ws + 29360128;      // [64 bh][64][2048]

    cvt_f32_bf16_k<<<4096, 256, 0, stream>>>(x, xb, 1048576);
    tr_f32_bf16_k<<<768, 256, 0, stream>>>(w_qkv, wqT, 1024, 3072);
    tr_f32_bf16_k<<<256, 256, 0, stream>>>(w_o, woT, 1024, 1024);
    gemm_bt_k<0><<<1536, 256, 0, stream>>>(xb, wqT, b_qkv, Qp, Kp, Vt, nullptr, 8192, 3072, 1024);
    attn_k<<<1024, 256, 0, stream>>>(Qp, Kp, Vt, xb);
    gemm_bt_k<1><<<512, 256, 0, stream>>>(xb, woT, b_o, nullptr, nullptr, nullptr, out, 8192, 1024, 1024);
}

// Round 8
// 212.587 us; speedup vs baseline: 1.8629x; 1.8629x over previous
//
#include <hip/hip_runtime.h>

typedef unsigned short u16;
typedef unsigned short u16x4 __attribute__((ext_vector_type(4), may_alias));
typedef unsigned short u16x8 __attribute__((ext_vector_type(8), may_alias));
typedef __bf16 bf16x8 __attribute__((ext_vector_type(8), may_alias));
typedef float f32x4 __attribute__((ext_vector_type(4), may_alias));

typedef __attribute__((address_space(1))) void gvoid_t;
typedef __attribute__((address_space(3))) void lvoid_t;

__device__ __forceinline__ void gld16(const void* g, void* l) {
    __builtin_amdgcn_global_load_lds((gvoid_t*)g, (lvoid_t*)l, 16, 0, 0);
}

__device__ __forceinline__ u16 f2bf(float f) {
    unsigned u = __builtin_bit_cast(unsigned, f);
    u += 0x7fffu + ((u >> 16) & 1u);
    return (u16)(u >> 16);
}

__device__ __forceinline__ unsigned cvt_pk_bf16(float lo, float hi) {
    unsigned r;
    asm("v_cvt_pk_bf16_f32 %0, %1, %2" : "=v"(r) : "v"(lo), "v"(hi));
    return r;
}

#define KSCALE 0.18033688011112042f  /* 0.125 * log2(e) */

// ---------------- fp32 -> bf16 elementwise ----------------
__global__ __launch_bounds__(256) void cvt_f32_bf16_k(const float* __restrict__ in,
                                                      u16* __restrict__ out, int n8) {
    int i = blockIdx.x * 256 + threadIdx.x;
    if (i >= n8) return;
    float4 a = reinterpret_cast<const float4*>(in)[2 * i];
    float4 c = reinterpret_cast<const float4*>(in)[2 * i + 1];
    u16x8 o;
    o[0] = f2bf(a.x); o[1] = f2bf(a.y); o[2] = f2bf(a.z); o[3] = f2bf(a.w);
    o[4] = f2bf(c.x); o[5] = f2bf(c.y); o[6] = f2bf(c.z); o[7] = f2bf(c.w);
    reinterpret_cast<u16x8*>(out)[i] = o;
}

// ---------------- fp32 [R][C] -> bf16 [C][R] transpose ----------------
__global__ __launch_bounds__(256) void tr_f32_bf16_k(const float* __restrict__ in,
                                                     u16* __restrict__ out, int R, int C) {
    __shared__ u16 t[64][73];
    int tc = C >> 6;
    int r0 = (blockIdx.x / tc) << 6, c0 = (blockIdx.x % tc) << 6;
    int lr = threadIdx.x >> 2;
    int lc = (threadIdx.x & 3) << 4;
    const float* src = in + (size_t)(r0 + lr) * C + c0 + lc;
#pragma unroll
    for (int j = 0; j < 16; j += 4) {
        float4 v = *reinterpret_cast<const float4*>(src + j);
        t[lr][lc + j + 0] = f2bf(v.x);
        t[lr][lc + j + 1] = f2bf(v.y);
        t[lr][lc + j + 2] = f2bf(v.z);
        t[lr][lc + j + 3] = f2bf(v.w);
    }
    __syncthreads();
    u16x8 o0, o1;
#pragma unroll
    for (int j = 0; j < 8; j++) { o0[j] = t[lc + j][lr]; o1[j] = t[lc + 8 + j][lr]; }
    u16* dst = out + (size_t)(c0 + lr) * R + r0 + lc;
    *reinterpret_cast<u16x8*>(dst) = o0;
    *reinterpret_cast<u16x8*>(dst + 8) = o1;
}

// ---------------- bf16 GEMM: C = A[M][K] * Bt[N][K]^T + bias ----------------
template <int MODE>
__global__ __launch_bounds__(256) void gemm_bt_k(const u16* __restrict__ A,
                                                 const u16* __restrict__ Bt,
                                                 const float* __restrict__ bias,
                                                 u16* __restrict__ Qp, u16* __restrict__ Kp,
                                                 u16* __restrict__ Vt,
                                                 float* __restrict__ Cf,
                                                 int M, int N, int K) {
    __shared__ u16 As[2][128 * 64];
    __shared__ u16 Bs[2][128 * 64];
    const int tid = threadIdx.x;
    const int l = tid & 63, w = tid >> 6;
    const int wm = w >> 1, wn = w & 1;
    const int l16 = l & 15, lg = l >> 4;
    const int tc = N >> 7;
    const int bm = blockIdx.x / tc, bn = blockIdx.x % tc;
    const u16* Ab = A + (size_t)(bm << 7) * K;
    const u16* Bb = Bt + (size_t)(bn << 7) * K;

    f32x4 acc[4][4];
#pragma unroll
    for (int mi = 0; mi < 4; mi++)
#pragma unroll
        for (int ni = 0; ni < 4; ni++)
#pragma unroll
            for (int q = 0; q < 4; q++) acc[mi][ni][q] = 0.f;

    auto stage = [&](int buf, int k0) {
#pragma unroll
        for (int i = 0; i < 4; i++) {
            int s = tid + (i << 8);
            int ub = ((i << 8) + (w << 6)) << 3;
            gld16(Ab + (size_t)(s >> 3) * K + k0 + ((s & 7) << 3), &As[buf][ub]);
            gld16(Bb + (size_t)(s >> 3) * K + k0 + ((s & 7) << 3), &Bs[buf][ub]);
        }
    };

    stage(0, 0);
    int cur = 0;
    for (int k0 = 0; k0 < K; k0 += 64) {
        __syncthreads();
        if (k0 + 64 < K) stage(cur ^ 1, k0 + 64);
        const u16* Asc = As[cur];
        const u16* Bsc = Bs[cur];
#pragma unroll
        for (int kk = 0; kk < 2; kk++) {
            bf16x8 af[4], bfr[4];
#pragma unroll
            for (int mi = 0; mi < 4; mi++)
                af[mi] = *reinterpret_cast<const bf16x8*>(
                    &Asc[((wm << 6) + (mi << 4) + l16) * 64 + (kk << 5) + (lg << 3)]);
#pragma unroll
            for (int ni = 0; ni < 4; ni++)
                bfr[ni] = *reinterpret_cast<const bf16x8*>(
                    &Bsc[((wn << 6) + (ni << 4) + l16) * 64 + (kk << 5) + (lg << 3)]);
#pragma unroll
            for (int mi = 0; mi < 4; mi++)
#pragma unroll
                for (int ni = 0; ni < 4; ni++)
                    acc[mi][ni] = __builtin_amdgcn_mfma_f32_16x16x32_bf16(af[mi], bfr[ni], acc[mi][ni], 0, 0, 0);
        }
        cur ^= 1;
    }

    const int rb = (bm << 7) + (wm << 6), cb = (bn << 7) + (wn << 6);
    if constexpr (MODE == 0) {
        const int sec = cb >> 10;
#pragma unroll
        for (int ni = 0; ni < 4; ni++) {
            const int col = cb + (ni << 4) + l16;
            const float bb = bias[col];
            const int d = col & 1023, h = d >> 6, dh = d & 63;
#pragma unroll
            for (int mi = 0; mi < 4; mi++) {
                const int row0 = rb + (mi << 4) + (lg << 2);
                const int bidx = row0 >> 11, n0 = row0 & 2047;
                const size_t base = (size_t)(bidx * 16 + h) * 131072;
                if (sec == 0) {
#pragma unroll
                    for (int r = 0; r < 4; r++)
                        Qp[base + (size_t)(n0 + r) * 64 + dh] = f2bf(acc[mi][ni][r] + bb);
                } else if (sec == 1) {
#pragma unroll
                    for (int r = 0; r < 4; r++)
                        Kp[base + (size_t)(n0 + r) * 64 + dh] = f2bf((acc[mi][ni][r] + bb) * KSCALE);
                } else {
                    u16x4 pk;
#pragma unroll
                    for (int r = 0; r < 4; r++) pk[r] = f2bf(acc[mi][ni][r] + bb);
                    *reinterpret_cast<u16x4*>(&Vt[base + (size_t)dh * 2048 + n0]) = pk;
                }
            }
        }
    } else {
#pragma unroll
        for (int ni = 0; ni < 4; ni++) {
            const int col = cb + (ni << 4) + l16;
            const float bb = bias[col];
#pragma unroll
            for (int mi = 0; mi < 4; mi++)
#pragma unroll
                for (int r = 0; r < 4; r++) {
                    const int row = rb + (mi << 4) + (lg << 2) + r;
                    Cf[(size_t)row * N + col] = acc[mi][ni][r] + bb;
                }
        }
    }
}

// ---------------- flash attention: LDS-staged K/V, block-cooperative ----------------
// Block = (bh, QT): 64 q-rows (4 waves x 16), kv tiles 0..QT (64 kv each).
// K/V double-buffered in LDS via global_load_lds (1 barrier/tile); T2 XOR swizzle
// (linear LDS dest + inverse-swizzled global src + swizzled read).
// XCD swizzle: each XCD gets 8 consecutive bh, heavy QT first.
__global__ __launch_bounds__(256, 3) void attn_k(const u16* __restrict__ Qp,
                                                 const u16* __restrict__ Kp,
                                                 const u16* __restrict__ Vt,
                                                 u16* __restrict__ Y) {
    __shared__ u16 Ks[2][64 * 64];
    __shared__ u16 Vs[2][64 * 64];
    __shared__ u16 P_lds[4][16 * 72];
    const int tid = threadIdx.x;
    const int l = tid & 63, w = tid >> 6;
    const int l16 = l & 15, lg = l >> 4;
    const int swz = (blockIdx.x & 7) * 256 + (blockIdx.x >> 3);
    const int bh = swz >> 5;                 // 8 consecutive bh per XCD chunk
    const int QT = 31 - (swz & 31);          // heavy first
    const int nt = QT + 1;
    const int b = bh >> 4, h = bh & 15;
    const u16* Qb = Qp + (size_t)bh * 131072;
    const u16* Kb = Kp + (size_t)bh * 131072;
    const u16* Vb = Vt + (size_t)bh * 131072;
    u16* pl = &P_lds[w][0];

    const int qrow0 = QT * 64 + w * 16;      // this wave's 16 q-rows
    bf16x8 qf[2];
#pragma unroll
    for (int kk = 0; kk < 2; kk++)
        qf[kk] = *reinterpret_cast<const bf16x8*>(
            Qb + (size_t)(qrow0 + l16) * 64 + kk * 32 + lg * 8);

    f32x4 o[4];
    float m_s = -1e30f, l_s = 0.f;
#pragma unroll
    for (int n = 0; n < 4; n++)
#pragma unroll
        for (int r = 0; r < 4; r++) o[n][r] = 0.f;

    const int lr = l >> 3;                   // 0..7: row within 8-row stage chunk
    const int sslot = (l & 7) ^ lr;          // inverse-swizzled source 16B-slot
    const int r0 = w * 16;                   // this wave's 16 staged rows
    auto stage = [&](int buf, int kv0) {
        gld16(Kb + (size_t)(kv0 + r0 + lr) * 64 + sslot * 8,       &Ks[buf][r0 * 64]);
        gld16(Kb + (size_t)(kv0 + r0 + 8 + lr) * 64 + sslot * 8,   &Ks[buf][(r0 + 8) * 64]);
        gld16(Vb + (size_t)(r0 + lr) * 2048 + kv0 + sslot * 8,     &Vs[buf][r0 * 64]);
        gld16(Vb + (size_t)(r0 + 8 + lr) * 2048 + kv0 + sslot * 8, &Vs[buf][(r0 + 8) * 64]);
    };

    stage(0, 0);
    int cur = 0;
    const int xs = l16 & 7;                  // read-side swizzle key (row & 7)
#pragma unroll 1
    for (int it = 0; it < nt; it++) {
        __syncthreads();                     // drains vmcnt -> buf[cur] staged
        if (it + 1 < nt) stage(cur ^ 1, (it + 1) * 64);
        // QK^T from LDS (swapped operands -> lane owns q-row l16, 16 kv in-lane)
        float s4[4][4];
#pragma unroll
        for (int t = 0; t < 4; t++) {
            f32x4 s;
            s[0] = s[1] = s[2] = s[3] = 0.f;
#pragma unroll
            for (int kk = 0; kk < 2; kk++) {
                bf16x8 kf = *reinterpret_cast<const bf16x8*>(
                    &Ks[cur][(t * 16 + l16) * 64 + ((kk * 4 + lg) ^ xs) * 8]);
                s = __builtin_amdgcn_mfma_f32_16x16x32_bf16(kf, qf[kk], s, 0, 0, 0);
            }
#pragma unroll
            for (int r = 0; r < 4; r++) s4[t][r] = s[r];
        }
        if (it == nt - 1) {                  // diagonal 64x64 block: causal mask
            const int qg = w * 16 + l16;
            const int kvb = lg * 4;
#pragma unroll
            for (int t = 0; t < 4; t++)
#pragma unroll
                for (int r = 0; r < 4; r++)
                    if (kvb + t * 16 + r > qg) s4[t][r] = -1e30f;
        }
        float mt[4];
#pragma unroll
        for (int t = 0; t < 4; t++)
            mt[t] = fmaxf(fmaxf(s4[t][0], s4[t][1]), fmaxf(s4[t][2], s4[t][3]));
        float mx = fmaxf(fmaxf(mt[0], mt[1]), fmaxf(mt[2], mt[3]));
        mx = fmaxf(mx, __shfl_xor(mx, 16, 64));
        mx = fmaxf(mx, __shfl_xor(mx, 32, 64));
        if (__any(mx - m_s > 8.0f)) {        // defer-max rescale
            float mn = fmaxf(m_s, mx);
            float al = __builtin_amdgcn_exp2f(m_s - mn);
            m_s = mn;
            l_s *= al;
#pragma unroll
            for (int r = 0; r < 4; r++) {
                float ar = __shfl(al, lg * 4 + r, 64);
#pragma unroll
                for (int n = 0; n < 4; n++) o[n][r] *= ar;
            }
        }
#pragma unroll
        for (int t = 0; t < 4; t++)
#pragma unroll
            for (int r = 0; r < 4; r++)
                s4[t][r] = __builtin_amdgcn_exp2f(s4[t][r] - m_s);
        float st[4];
#pragma unroll
        for (int t = 0; t < 4; t++)
            st[t] = (s4[t][0] + s4[t][1]) + (s4[t][2] + s4[t][3]);
        float sm = (st[0] + st[1]) + (st[2] + st[3]);
        sm += __shfl_xor(sm, 16, 64);
        sm += __shfl_xor(sm, 32, 64);
        l_s += sm;
#pragma unroll
        for (int t = 0; t < 4; t++) {
            uint2 pk;
            pk.x = cvt_pk_bf16(s4[t][0], s4[t][1]);
            pk.y = cvt_pk_bf16(s4[t][2], s4[t][3]);
            *reinterpret_cast<uint2*>(pl + l16 * 72 + t * 16 + lg * 4) = pk;
        }
        bf16x8 pa[2];
#pragma unroll
        for (int kk2 = 0; kk2 < 2; kk2++)
            pa[kk2] = *reinterpret_cast<const bf16x8*>(pl + l16 * 72 + kk2 * 32 + lg * 8);
#pragma unroll
        for (int n = 0; n < 4; n++) {
            bf16x8 v0 = *reinterpret_cast<const bf16x8*>(
                &Vs[cur][(n * 16 + l16) * 64 + ((0 * 4 + lg) ^ xs) * 8]);
            bf16x8 v1 = *reinterpret_cast<const bf16x8*>(
                &Vs[cur][(n * 16 + l16) * 64 + ((1 * 4 + lg) ^ xs) * 8]);
            o[n] = __builtin_amdgcn_mfma_f32_16x16x32_bf16(pa[0], v0, o[n], 0, 0, 0);
            o[n] = __builtin_amdgcn_mfma_f32_16x16x32_bf16(pa[1], v1, o[n], 0, 0, 0);
        }
        cur ^= 1;
    }
    // epilogue: lane's o covers q-rows qrow0 + lg*4 + r, cols h*64 + n*16 + l16
#pragma unroll
    for (int r = 0; r < 4; r++) {
        const float li = __shfl(l_s, lg * 4 + r, 64);
        const float inv = 1.0f / li;
        const size_t row = (size_t)(b * 2048 + qrow0 + lg * 4 + r);
#pragma unroll
        for (int n = 0; n < 4; n++)
            Y[row * 1024 + h * 64 + n * 16 + l16] = f2bf(o[n][r] * inv);
    }
}

extern "C" void kernel_launch(void* const* d_in, const int* in_sizes, int n_in,
                              void* d_out, int out_size, void* d_ws, size_t ws_size,
                              hipStream_t stream) {
    const float* x     = (const float*)d_in[0];
    const float* w_qkv = (const float*)d_in[1];
    const float* b_qkv = (const float*)d_in[2];
    const float* w_o   = (const float*)d_in[3];
    const float* b_o   = (const float*)d_in[4];
    float* out = (float*)d_out;

    u16* ws  = (u16*)d_ws;
    u16* xb  = ws;                 // [8192][1024] x bf16; reused as attention output Y
    u16* wqT = ws + 8388608;       // [3072][1024]
    u16* woT = ws + 11534336;      // [1024][1024]
    u16* Qp  = ws + 12582912;      // [64 bh][2048][64]
    u16* Kp  = ws + 20971520;      // [64 bh][2048][64] (pre-scaled by 0.125*log2e)
    u16* Vt  = ws + 29360128;      // [64 bh][64][2048]

    cvt_f32_bf16_k<<<4096, 256, 0, stream>>>(x, xb, 1048576);
    tr_f32_bf16_k<<<768, 256, 0, stream>>>(w_qkv, wqT, 1024, 3072);
    tr_f32_bf16_k<<<256, 256, 0, stream>>>(w_o, woT, 1024, 1024);
    gemm_bt_k<0><<<1536, 256, 0, stream>>>(xb, wqT, b_qkv, Qp, Kp, Vt, nullptr, 8192, 3072, 1024);
    attn_k<<<2048, 256, 0, stream>>>(Qp, Kp, Vt, xb);
    gemm_bt_k<1><<<512, 256, 0, stream>>>(xb, woT, b_o, nullptr, nullptr, nullptr, out, 8192, 1024, 1024);
}

// Round 9
// 200.960 us; speedup vs baseline: 1.9707x; 1.0579x over previous
//
#include <hip/hip_runtime.h>

typedef unsigned short u16;
typedef unsigned short u16x4 __attribute__((ext_vector_type(4), may_alias));
typedef unsigned short u16x8 __attribute__((ext_vector_type(8), may_alias));
typedef __bf16 bf16x8 __attribute__((ext_vector_type(8), may_alias));
typedef float f32x4 __attribute__((ext_vector_type(4), may_alias));

typedef __attribute__((address_space(1))) void gvoid_t;
typedef __attribute__((address_space(3))) void lvoid_t;

__device__ __forceinline__ void gld16(const void* g, void* l) {
    __builtin_amdgcn_global_load_lds((gvoid_t*)g, (lvoid_t*)l, 16, 0, 0);
}

__device__ __forceinline__ u16 f2bf(float f) {
    unsigned u = __builtin_bit_cast(unsigned, f);
    u += 0x7fffu + ((u >> 16) & 1u);
    return (u16)(u >> 16);
}

__device__ __forceinline__ unsigned cvt_pk_bf16(float lo, float hi) {
    unsigned r;
    asm("v_cvt_pk_bf16_f32 %0, %1, %2" : "=v"(r) : "v"(lo), "v"(hi));
    return r;
}

#define KSCALE 0.18033688011112042f  /* 0.125 * log2(e) */

// ---------------- fp32 -> bf16 elementwise ----------------
__global__ __launch_bounds__(256) void cvt_f32_bf16_k(const float* __restrict__ in,
                                                      u16* __restrict__ out, int n8) {
    int i = blockIdx.x * 256 + threadIdx.x;
    if (i >= n8) return;
    float4 a = reinterpret_cast<const float4*>(in)[2 * i];
    float4 c = reinterpret_cast<const float4*>(in)[2 * i + 1];
    u16x8 o;
    o[0] = f2bf(a.x); o[1] = f2bf(a.y); o[2] = f2bf(a.z); o[3] = f2bf(a.w);
    o[4] = f2bf(c.x); o[5] = f2bf(c.y); o[6] = f2bf(c.z); o[7] = f2bf(c.w);
    reinterpret_cast<u16x8*>(out)[i] = o;
}

// ---------------- fp32 [R][C] -> bf16 [C][R] transpose ----------------
__global__ __launch_bounds__(256) void tr_f32_bf16_k(const float* __restrict__ in,
                                                     u16* __restrict__ out, int R, int C) {
    __shared__ u16 t[64][73];
    int tc = C >> 6;
    int r0 = (blockIdx.x / tc) << 6, c0 = (blockIdx.x % tc) << 6;
    int lr = threadIdx.x >> 2;
    int lc = (threadIdx.x & 3) << 4;
    const float* src = in + (size_t)(r0 + lr) * C + c0 + lc;
#pragma unroll
    for (int j = 0; j < 16; j += 4) {
        float4 v = *reinterpret_cast<const float4*>(src + j);
        t[lr][lc + j + 0] = f2bf(v.x);
        t[lr][lc + j + 1] = f2bf(v.y);
        t[lr][lc + j + 2] = f2bf(v.z);
        t[lr][lc + j + 3] = f2bf(v.w);
    }
    __syncthreads();
    u16x8 o0, o1;
#pragma unroll
    for (int j = 0; j < 8; j++) { o0[j] = t[lc + j][lr]; o1[j] = t[lc + 8 + j][lr]; }
    u16* dst = out + (size_t)(c0 + lr) * R + r0 + lc;
    *reinterpret_cast<u16x8*>(dst) = o0;
    *reinterpret_cast<u16x8*>(dst + 8) = o1;
}

// ---------------- bf16 GEMM (m97 structure): single LDS buffer, 2 barriers/K-step ----------------
template <int MODE>
__global__ __launch_bounds__(256, 4) void gemm_bt_k(const u16* __restrict__ A,
                                                    const u16* __restrict__ Bt,
                                                    const float* __restrict__ bias,
                                                    u16* __restrict__ Qp, u16* __restrict__ Kp,
                                                    u16* __restrict__ Vt,
                                                    float* __restrict__ Cf,
                                                    int M, int N, int K) {
    __shared__ u16 As[128 * 64];
    __shared__ u16 Bs[128 * 64];
    const int tid = threadIdx.x;
    const int l = tid & 63, w = tid >> 6;
    const int wm = w >> 1, wn = w & 1;
    const int l16 = l & 15, lg = l >> 4;
    const int tc = N >> 7;
    const int bm = blockIdx.x / tc, bn = blockIdx.x % tc;
    const u16* Ab = A + (size_t)(bm << 7) * K;
    const u16* Bb = Bt + (size_t)(bn << 7) * K;

    f32x4 acc[4][4];
#pragma unroll
    for (int mi = 0; mi < 4; mi++)
#pragma unroll
        for (int ni = 0; ni < 4; ni++)
#pragma unroll
            for (int q = 0; q < 4; q++) acc[mi][ni][q] = 0.f;

    auto stage = [&](int k0) {
#pragma unroll
        for (int i = 0; i < 4; i++) {
            int s = tid + (i << 8);
            int ub = ((i << 8) + (w << 6)) << 3;   // wave-uniform LDS elem offset
            gld16(Ab + (size_t)(s >> 3) * K + k0 + ((s & 7) << 3), &As[ub]);
            gld16(Bb + (size_t)(s >> 3) * K + k0 + ((s & 7) << 3), &Bs[ub]);
        }
    };

    stage(0);
    for (int k0 = 0; k0 < K; k0 += 64) {
        __syncthreads();                 // compiler drains vmcnt before barrier -> tile staged
#pragma unroll
        for (int kk = 0; kk < 2; kk++) {
            bf16x8 af[4], bfr[4];
#pragma unroll
            for (int mi = 0; mi < 4; mi++)
                af[mi] = *reinterpret_cast<const bf16x8*>(
                    &As[((wm << 6) + (mi << 4) + l16) * 64 + (kk << 5) + (lg << 3)]);
#pragma unroll
            for (int ni = 0; ni < 4; ni++)
                bfr[ni] = *reinterpret_cast<const bf16x8*>(
                    &Bs[((wn << 6) + (ni << 4) + l16) * 64 + (kk << 5) + (lg << 3)]);
#pragma unroll
            for (int mi = 0; mi < 4; mi++)
#pragma unroll
                for (int ni = 0; ni < 4; ni++)
                    acc[mi][ni] = __builtin_amdgcn_mfma_f32_16x16x32_bf16(af[mi], bfr[ni], acc[mi][ni], 0, 0, 0);
        }
        __syncthreads();                 // all waves done reading LDS
        if (k0 + 64 < K) stage(k0 + 64); // loads fly while other blocks' waves compute
    }

    const int rb = (bm << 7) + (wm << 6), cb = (bn << 7) + (wn << 6);
    if constexpr (MODE == 0) {
        const int sec = cb >> 10;   // 0=Q 1=K 2=V, uniform per block
#pragma unroll
        for (int ni = 0; ni < 4; ni++) {
            const int col = cb + (ni << 4) + l16;
            const float bb = bias[col];
            const int d = col & 1023, h = d >> 6, dh = d & 63;
#pragma unroll
            for (int mi = 0; mi < 4; mi++) {
                const int row0 = rb + (mi << 4) + (lg << 2);
                const int bidx = row0 >> 11, n0 = row0 & 2047;
                const size_t base = (size_t)(bidx * 16 + h) * 131072;
                if (sec == 0) {
#pragma unroll
                    for (int r = 0; r < 4; r++)
                        Qp[base + (size_t)(n0 + r) * 64 + dh] = f2bf(acc[mi][ni][r] + bb);
                } else if (sec == 1) {
#pragma unroll
                    for (int r = 0; r < 4; r++)
                        Kp[base + (size_t)(n0 + r) * 64 + dh] = f2bf((acc[mi][ni][r] + bb) * KSCALE);
                } else {
                    u16x4 pk;
#pragma unroll
                    for (int r = 0; r < 4; r++) pk[r] = f2bf(acc[mi][ni][r] + bb);
                    *reinterpret_cast<u16x4*>(&Vt[base + (size_t)dh * 2048 + n0]) = pk;
                }
            }
        }
    } else {
#pragma unroll
        for (int ni = 0; ni < 4; ni++) {
            const int col = cb + (ni << 4) + l16;
            const float bb = bias[col];
#pragma unroll
            for (int mi = 0; mi < 4; mi++)
#pragma unroll
                for (int r = 0; r < 4; r++) {
                    const int row = rb + (mi << 4) + (lg << 2) + r;
                    Cf[(size_t)row * N + col] = acc[mi][ni][r] + bb;
                }
        }
    }
}

// ---------------- flash attention: LDS-staged K/V, block-cooperative (r8, unchanged) ----------------
__global__ __launch_bounds__(256, 3) void attn_k(const u16* __restrict__ Qp,
                                                 const u16* __restrict__ Kp,
                                                 const u16* __restrict__ Vt,
                                                 u16* __restrict__ Y) {
    __shared__ u16 Ks[2][64 * 64];
    __shared__ u16 Vs[2][64 * 64];
    __shared__ u16 P_lds[4][16 * 72];
    const int tid = threadIdx.x;
    const int l = tid & 63, w = tid >> 6;
    const int l16 = l & 15, lg = l >> 4;
    const int swz = (blockIdx.x & 7) * 256 + (blockIdx.x >> 3);
    const int bh = swz >> 5;                 // 8 consecutive bh per XCD chunk
    const int QT = 31 - (swz & 31);          // heavy first
    const int nt = QT + 1;
    const int b = bh >> 4, h = bh & 15;
    const u16* Qb = Qp + (size_t)bh * 131072;
    const u16* Kb = Kp + (size_t)bh * 131072;
    const u16* Vb = Vt + (size_t)bh * 131072;
    u16* pl = &P_lds[w][0];

    const int qrow0 = QT * 64 + w * 16;      // this wave's 16 q-rows
    bf16x8 qf[2];
#pragma unroll
    for (int kk = 0; kk < 2; kk++)
        qf[kk] = *reinterpret_cast<const bf16x8*>(
            Qb + (size_t)(qrow0 + l16) * 64 + kk * 32 + lg * 8);

    f32x4 o[4];
    float m_s = -1e30f, l_s = 0.f;
#pragma unroll
    for (int n = 0; n < 4; n++)
#pragma unroll
        for (int r = 0; r < 4; r++) o[n][r] = 0.f;

    const int lr = l >> 3;                   // 0..7: row within 8-row stage chunk
    const int sslot = (l & 7) ^ lr;          // inverse-swizzled source 16B-slot
    const int r0 = w * 16;                   // this wave's 16 staged rows
    auto stage = [&](int buf, int kv0) {
        gld16(Kb + (size_t)(kv0 + r0 + lr) * 64 + sslot * 8,       &Ks[buf][r0 * 64]);
        gld16(Kb + (size_t)(kv0 + r0 + 8 + lr) * 64 + sslot * 8,   &Ks[buf][(r0 + 8) * 64]);
        gld16(Vb + (size_t)(r0 + lr) * 2048 + kv0 + sslot * 8,     &Vs[buf][r0 * 64]);
        gld16(Vb + (size_t)(r0 + 8 + lr) * 2048 + kv0 + sslot * 8, &Vs[buf][(r0 + 8) * 64]);
    };

    stage(0, 0);
    int cur = 0;
    const int xs = l16 & 7;                  // read-side swizzle key (row & 7)
#pragma unroll 1
    for (int it = 0; it < nt; it++) {
        __syncthreads();                     // drains vmcnt -> buf[cur] staged
        if (it + 1 < nt) stage(cur ^ 1, (it + 1) * 64);
        // QK^T from LDS (swapped operands -> lane owns q-row l16, 16 kv in-lane)
        float s4[4][4];
#pragma unroll
        for (int t = 0; t < 4; t++) {
            f32x4 s;
            s[0] = s[1] = s[2] = s[3] = 0.f;
#pragma unroll
            for (int kk = 0; kk < 2; kk++) {
                bf16x8 kf = *reinterpret_cast<const bf16x8*>(
                    &Ks[cur][(t * 16 + l16) * 64 + ((kk * 4 + lg) ^ xs) * 8]);
                s = __builtin_amdgcn_mfma_f32_16x16x32_bf16(kf, qf[kk], s, 0, 0, 0);
            }
#pragma unroll
            for (int r = 0; r < 4; r++) s4[t][r] = s[r];
        }
        if (it == nt - 1) {                  // diagonal 64x64 block: causal mask
            const int qg = w * 16 + l16;
            const int kvb = lg * 4;
#pragma unroll
            for (int t = 0; t < 4; t++)
#pragma unroll
                for (int r = 0; r < 4; r++)
                    if (kvb + t * 16 + r > qg) s4[t][r] = -1e30f;
        }
        float mt[4];
#pragma unroll
        for (int t = 0; t < 4; t++)
            mt[t] = fmaxf(fmaxf(s4[t][0], s4[t][1]), fmaxf(s4[t][2], s4[t][3]));
        float mx = fmaxf(fmaxf(mt[0], mt[1]), fmaxf(mt[2], mt[3]));
        mx = fmaxf(mx, __shfl_xor(mx, 16, 64));
        mx = fmaxf(mx, __shfl_xor(mx, 32, 64));
        if (__any(mx - m_s > 8.0f)) {        // defer-max rescale
            float mn = fmaxf(m_s, mx);
            float al = __builtin_amdgcn_exp2f(m_s - mn);
            m_s = mn;
            l_s *= al;
#pragma unroll
            for (int r = 0; r < 4; r++) {
                float ar = __shfl(al, lg * 4 + r, 64);
#pragma unroll
                for (int n = 0; n < 4; n++) o[n][r] *= ar;
            }
        }
#pragma unroll
        for (int t = 0; t < 4; t++)
#pragma unroll
            for (int r = 0; r < 4; r++)
                s4[t][r] = __builtin_amdgcn_exp2f(s4[t][r] - m_s);
        float st[4];
#pragma unroll
        for (int t = 0; t < 4; t++)
            st[t] = (s4[t][0] + s4[t][1]) + (s4[t][2] + s4[t][3]);
        float sm = (st[0] + st[1]) + (st[2] + st[3]);
        sm += __shfl_xor(sm, 16, 64);
        sm += __shfl_xor(sm, 32, 64);
        l_s += sm;
#pragma unroll
        for (int t = 0; t < 4; t++) {
            uint2 pk;
            pk.x = cvt_pk_bf16(s4[t][0], s4[t][1]);
            pk.y = cvt_pk_bf16(s4[t][2], s4[t][3]);
            *reinterpret_cast<uint2*>(pl + l16 * 72 + t * 16 + lg * 4) = pk;
        }
        bf16x8 pa[2];
#pragma unroll
        for (int kk2 = 0; kk2 < 2; kk2++)
            pa[kk2] = *reinterpret_cast<const bf16x8*>(pl + l16 * 72 + kk2 * 32 + lg * 8);
#pragma unroll
        for (int n = 0; n < 4; n++) {
            bf16x8 v0 = *reinterpret_cast<const bf16x8*>(
                &Vs[cur][(n * 16 + l16) * 64 + ((0 * 4 + lg) ^ xs) * 8]);
            bf16x8 v1 = *reinterpret_cast<const bf16x8*>(
                &Vs[cur][(n * 16 + l16) * 64 + ((1 * 4 + lg) ^ xs) * 8]);
            o[n] = __builtin_amdgcn_mfma_f32_16x16x32_bf16(pa[0], v0, o[n], 0, 0, 0);
            o[n] = __builtin_amdgcn_mfma_f32_16x16x32_bf16(pa[1], v1, o[n], 0, 0, 0);
        }
        cur ^= 1;
    }
    // epilogue
#pragma unroll
    for (int r = 0; r < 4; r++) {
        const float li = __shfl(l_s, lg * 4 + r, 64);
        const float inv = 1.0f / li;
        const size_t row = (size_t)(b * 2048 + qrow0 + lg * 4 + r);
#pragma unroll
        for (int n = 0; n < 4; n++)
            Y[row * 1024 + h * 64 + n * 16 + l16] = f2bf(o[n][r] * inv);
    }
}

extern "C" void kernel_launch(void* const* d_in, const int* in_sizes, int n_in,
                              void* d_out, int out_size, void* d_ws, size_t ws_size,
                              hipStream_t stream) {
    const float* x     = (const float*)d_in[0];
    const float* w_qkv = (const float*)d_in[1];
    const float* b_qkv = (const float*)d_in[2];
    const float* w_o   = (const float*)d_in[3];
    const float* b_o   = (const float*)d_in[4];
    float* out = (float*)d_out;

    u16* ws  = (u16*)d_ws;
    u16* xb  = ws;                 // [8192][1024] x bf16; reused as attention output Y
    u16* wqT = ws + 8388608;       // [3072][1024]
    u16* woT = ws + 11534336;      // [1024][1024]
    u16* Qp  = ws + 12582912;      // [64 bh][2048][64]
    u16* Kp  = ws + 20971520;      // [64 bh][2048][64] (pre-scaled by 0.125*log2e)
    u16* Vt  = ws + 29360128;      // [64 bh][64][2048]

    cvt_f32_bf16_k<<<4096, 256, 0, stream>>>(x, xb, 1048576);
    tr_f32_bf16_k<<<768, 256, 0, stream>>>(w_qkv, wqT, 1024, 3072);
    tr_f32_bf16_k<<<256, 256, 0, stream>>>(w_o, woT, 1024, 1024);
    gemm_bt_k<0><<<1536, 256, 0, stream>>>(xb, wqT, b_qkv, Qp, Kp, Vt, nullptr, 8192, 3072, 1024);
    attn_k<<<2048, 256, 0, stream>>>(Qp, Kp, Vt, xb);
    gemm_bt_k<1><<<512, 256, 0, stream>>>(xb, woT, b_o, nullptr, nullptr, nullptr, out, 8192, 1024, 1024);
}